// Round 1
// baseline (101.651 us; speedup 1.0000x reference)
//
#include <hip/hip_runtime.h>
#include <hip/hip_cooperative_groups.h>

namespace cg = cooperative_groups;

#define W_N 9216              // 32*32*3*3 floats
#define QX_PER_N (34*34*32)   // 36992 B haloed NHWC plane per n
#define QX_BYTES (8*QX_PER_N) // 295936 B
#define QX_INT4 (QX_BYTES/16) // 18496

static __device__ __forceinline__ int dot4(int a, int b, int acc) {
#if defined(__has_builtin)
#if __has_builtin(__builtin_amdgcn_sdot4)
  return __builtin_amdgcn_sdot4(a, b, acc, false);
#define DOT4_DONE 1
#endif
#endif
#ifndef DOT4_DONE
  #pragma unroll
  for (int k = 0; k < 4; k++)
    acc += ((a >> (8*k)) << 24 >> 24) * ((b >> (8*k)) << 24 >> 24);
  return acc;
#endif
}

// ---- k_prep (cooperative, 256 blocks x 256 threads):
// Phase A: x absmax partials (1 float4/thread), per-block redundant w absmax
//          (36 KB L2 broadcast -> sw needs no global reduce), zero qx.
// grid.sync()
// Phase B: redundant per-block reduce of 256 x-partials -> sf;
//          threads 32..67 quantize 36 weights each -> qw_r [o][k9][c];
//          threads 0..31 quantize 32 pixels each -> haloed NHWC qx.
__global__ __launch_bounds__(256) void k_prep(
    const float* __restrict__ x, const float* __restrict__ w,
    float* __restrict__ partials, float* __restrict__ sfsw,
    signed char* __restrict__ qw_r, signed char* __restrict__ qx) {
  __shared__ float red[256];
  int b = blockIdx.x, t = threadIdx.x;
  int gid = b * 256 + t;

  // x absmax: 256*256 threads cover all 65536 float4 of x
  float4 v = ((const float4*)x)[gid];
  float mx = fmaxf(fmaxf(fabsf(v.x), fabsf(v.y)), fmaxf(fabsf(v.z), fabsf(v.w)));

  // w absmax: each block scans the whole (36 KB) weight tensor
  float mw = 0.f;
  #pragma unroll
  for (int i = t; i < W_N / 4; i += 256) {
    float4 u = ((const float4*)w)[i];
    mw = fmaxf(mw, fmaxf(fmaxf(fabsf(u.x), fabsf(u.y)), fmaxf(fabsf(u.z), fabsf(u.w))));
  }

  // zero whole qx (halo included; interior overwritten after sync)
  if (gid < QX_INT4) ((int4*)qx)[gid] = make_int4(0, 0, 0, 0);

  // block-reduce mx -> partials[b]
  red[t] = mx;
  __syncthreads();
  #pragma unroll
  for (int s = 128; s >= 1; s >>= 1) {
    if (t < s) red[t] = fmaxf(red[t], red[t + s]);
    __syncthreads();
  }
  if (t == 0) partials[b] = red[0];
  // block-reduce mw (safe to overwrite red: last loop iter ended in syncthreads,
  // and red[0] is only re-read by t==0 before its own write)
  red[t] = mw;
  __syncthreads();
  #pragma unroll
  for (int s = 128; s >= 1; s >>= 1) {
    if (t < s) red[t] = fmaxf(red[t], red[t + s]);
    __syncthreads();
  }
  float sw = red[0] / 127.f;

  cg::this_grid().sync();

  // sf: every block redundantly reduces the 256 partials
  red[t] = partials[t];
  __syncthreads();
  #pragma unroll
  for (int s = 128; s >= 1; s >>= 1) {
    if (t < s) red[t] = fmaxf(red[t], red[t + s]);
    __syncthreads();
  }
  float sf = red[0] / 127.f;
  float inv_sf = 1.f / sf;

  if (gid == 0) { sfsw[0] = sf; sfsw[1] = sw; }

  // weight quant: 256 blocks * 36 elems = 9216; src w[o][c][ky][kx]
  if (t >= 32 && t < 68) {
    int i = b * 36 + (t - 32);
    int o = i / 288, rem = i % 288;
    int c = rem / 9, k9 = rem % 9;
    float r = rintf(w[i] / sw);              // round half-to-even, like jnp.round
    r = fminf(fmaxf(r, -128.f), 127.f);
    qw_r[(o * 9 + k9) * 32 + c] = (signed char)(int)r;
  }

  // x quant: 256 blocks * 32 pixels = 8192; NCHW -> haloed NHWC int8
  if (t < 32) {
    int p = b * 32 + t;                      // pixel id
    int n = p >> 10, hw = p & 1023;
    int h = hw >> 5, ww = hw & 31;
    int q[8];
    #pragma unroll
    for (int g = 0; g < 8; g++) {
      int packed = 0;
      #pragma unroll
      for (int j = 0; j < 4; j++) {
        int c = g * 4 + j;
        float vv = x[n * 32768 + c * 1024 + hw];   // 128 B coalesced per c-step
        float rr = fminf(fmaxf(rintf(vv * inv_sf), -128.f), 127.f);
        packed |= ((int)rr & 0xff) << (8 * j);
      }
      q[g] = packed;
    }
    int4* dst = (int4*)(qx + n * QX_PER_N + ((h + 1) * 34 + (ww + 1)) * 32);
    dst[0] = make_int4(q[0], q[1], q[2], q[3]);
    dst[1] = make_int4(q[4], q[5], q[6], q[7]);
  }
}

// ---- k_conv: unchanged proven kernel. 1024 blocks = (n, o, strip), 1 pixel/thread.
// No LDS, no barriers. Patch rows are 96 B contiguous in haloed NHWC.
__global__ __launch_bounds__(256) void k_conv(
    const signed char* __restrict__ qx, const signed char* __restrict__ qw_r,
    const float* __restrict__ bias, const float* __restrict__ sfsw,
    float* __restrict__ out) {
  int b = blockIdx.x;
  int strip = b & 3;
  int o = (b >> 2) & 31;
  int n = b >> 7;
  int t = threadIdx.x;
  int h = strip * 8 + (t >> 5);
  int w = t & 31;

  const signed char* qxn = qx + n * QX_PER_N;
  const int* wq = (const int*)qw_r + o * 72;   // uniform per block -> s_load

  int acc = 0;
  #pragma unroll
  for (int ky = 0; ky < 3; ky++) {
    const int4* row = (const int4*)(qxn + ((h + ky) * 34 + w) * 32);  // 96 B window
    int4 p0 = row[0], p1 = row[1], p2 = row[2], p3 = row[3], p4 = row[4], p5 = row[5];
    const int* wr = wq + ky * 24;
    acc = dot4(p0.x, wr[0],  acc); acc = dot4(p0.y, wr[1],  acc);
    acc = dot4(p0.z, wr[2],  acc); acc = dot4(p0.w, wr[3],  acc);
    acc = dot4(p1.x, wr[4],  acc); acc = dot4(p1.y, wr[5],  acc);
    acc = dot4(p1.z, wr[6],  acc); acc = dot4(p1.w, wr[7],  acc);
    acc = dot4(p2.x, wr[8],  acc); acc = dot4(p2.y, wr[9],  acc);
    acc = dot4(p2.z, wr[10], acc); acc = dot4(p2.w, wr[11], acc);
    acc = dot4(p3.x, wr[12], acc); acc = dot4(p3.y, wr[13], acc);
    acc = dot4(p3.z, wr[14], acc); acc = dot4(p3.w, wr[15], acc);
    acc = dot4(p4.x, wr[16], acc); acc = dot4(p4.y, wr[17], acc);
    acc = dot4(p4.z, wr[18], acc); acc = dot4(p4.w, wr[19], acc);
    acc = dot4(p5.x, wr[20], acc); acc = dot4(p5.y, wr[21], acc);
    acc = dot4(p5.z, wr[22], acc); acc = dot4(p5.w, wr[23], acc);
  }

  float scale = sfsw[0] * sfsw[1];
  out[(n * 32 + o) * 1024 + h * 32 + w] = scale * (float)acc + bias[o];
}

extern "C" void kernel_launch(void* const* d_in, const int* in_sizes, int n_in,
                              void* d_out, int out_size, void* d_ws, size_t ws_size,
                              hipStream_t stream) {
  (void)in_sizes; (void)n_in; (void)out_size; (void)ws_size;
  const float* x    = (const float*)d_in[0];  // (8,32,32,32)
  const float* w    = (const float*)d_in[1];  // (32,32,3,3)
  const float* bias = (const float*)d_in[2];  // (32,)
  // d_in[3] (lut) unused: lut[i,j] = (i-128)*(j-128) analytically.
  float* out = (float*)d_out;

  char* ws = (char*)d_ws;
  float*       partials = (float*)(ws + 0);        // 256 floats
  float*       sfsw     = (float*)(ws + 1024);     // 2 floats
  signed char* qw_r     = (signed char*)(ws + 2048);   // 9216 B, [o][k9][c]
  signed char* qx       = (signed char*)(ws + 16384);  // 295936 B haloed NHWC

  void* args[6] = { (void*)&x, (void*)&w, (void*)&partials,
                    (void*)&sfsw, (void*)&qw_r, (void*)&qx };
  hipLaunchCooperativeKernel((const void*)k_prep, dim3(256), dim3(256),
                             args, 0, stream);
  k_conv<<<1024, 256, 0, stream>>>(qx, qw_r, bias, sfsw, out);
}

// Round 2
// 69.271 us; speedup vs baseline: 1.4674x; 1.4674x over previous
//
#include <hip/hip_runtime.h>

#define W_N 9216              // 32*32*3*3 floats

static __device__ __forceinline__ int dot4(int a, int b, int acc) {
#if defined(__has_builtin)
#if __has_builtin(__builtin_amdgcn_sdot4)
  return __builtin_amdgcn_sdot4(a, b, acc, false);
#define DOT4_DONE 1
#endif
#endif
#ifndef DOT4_DONE
  #pragma unroll
  for (int k = 0; k < 4; k++)
    acc += ((a >> (8*k)) << 24 >> 24) * ((b >> (8*k)) << 24 >> 24);
  return acc;
#endif
}

// ---- k1 (65 blocks x 256):
//   blocks 0..63 : x absmax partials (4 float4/thread; identical to proven kernel)
//   block  64    : w absmax (in-block) + quantize/reorder w -> qw_r [o][k9][c], sfsw[1]=sw
__global__ __launch_bounds__(256) void k_absmax_wq(
    const float4* __restrict__ x4, const float* __restrict__ w,
    float* __restrict__ partials, float* __restrict__ sfsw,
    signed char* __restrict__ qw_r) {
  __shared__ float red[256];
  __shared__ float s_sw;
  int b = blockIdx.x, t = threadIdx.x;

  if (b < 64) {
    float m = 0.f;
    #pragma unroll
    for (int k = 0; k < 4; k++) {
      float4 v = x4[b * 1024 + k * 256 + t];
      m = fmaxf(m, fmaxf(fmaxf(fabsf(v.x), fabsf(v.y)), fmaxf(fabsf(v.z), fabsf(v.w))));
    }
    red[t] = m;
    __syncthreads();
    #pragma unroll
    for (int s = 128; s >= 1; s >>= 1) {
      if (t < s) red[t] = fmaxf(red[t], red[t + s]);
      __syncthreads();
    }
    if (t == 0) partials[b] = red[0];
    return;
  }

  // block 64: weights. 2304 float4 -> 9/thread.
  const float4* w4 = (const float4*)w;
  float m = 0.f;
  #pragma unroll
  for (int j = 0; j < 9; j++) {
    float4 v = w4[t + 256 * j];
    m = fmaxf(m, fmaxf(fmaxf(fabsf(v.x), fabsf(v.y)), fmaxf(fabsf(v.z), fabsf(v.w))));
  }
  red[t] = m;
  __syncthreads();
  #pragma unroll
  for (int s = 128; s >= 1; s >>= 1) {
    if (t < s) red[t] = fmaxf(red[t], red[t + s]);
    __syncthreads();
  }
  if (t == 0) { s_sw = red[0] / 127.f; sfsw[1] = s_sw; }
  __syncthreads();
  float sw = s_sw;
  // quantize + reorder: src w[o][c][ky][kx], i = o*288 + c*9 + k9
  #pragma unroll
  for (int j = 0; j < 36; j++) {
    int i = t + 256 * j;
    int o = i / 288, rem = i % 288;
    int c = rem / 9, k9 = rem % 9;
    float r = rintf(w[i] / sw);          // round half-to-even, like jnp.round
    r = fminf(fmaxf(r, -128.f), 127.f);
    qw_r[(o * 9 + k9) * 32 + c] = (signed char)(int)r;
  }
}

// ---- k2 (256 blocks = 8n x 16hpair x 2ohalf, 256 threads):
//   phase 0: issue x loads (regs), reduce 64 partials -> sf (redundant per block)
//   phase 1: quantize 4 haloed rows into LDS qxt[4][34][8] (NHWC int8, packed int)
//   phase 2: conv. wave-uniform o (4 per wave), 18-int4 patch regs reused across o.
__global__ __launch_bounds__(256) void k_fused(
    const float* __restrict__ x, const float* __restrict__ partials,
    const float* __restrict__ sfsw, const signed char* __restrict__ qw_r,
    const float* __restrict__ bias, float* __restrict__ out) {
  __shared__ float red[64];
  __shared__ float s_sf;
  __shared__ __align__(16) int qxt[4][34][8];   // 4352 B haloed NHWC tile

  int b = blockIdx.x, t = threadIdx.x;
  int n = b >> 5, hpair = (b >> 1) & 15, ohalf = b & 1;
  int h0 = hpair * 2;

  // issue global x loads early (no sf dependency)
  int w = t & 31, g = t >> 5;
  float xv[4][4];
  #pragma unroll
  for (int r = 0; r < 4; r++) {
    int y = h0 - 1 + r;
    bool valid = (y >= 0) && (y < 32);
    #pragma unroll
    for (int j = 0; j < 4; j++) {
      int c = g * 4 + j;
      xv[r][j] = valid ? x[n * 32768 + c * 1024 + y * 32 + w] : 0.f;
    }
  }

  // sf: redundant per-block reduce of the 64 partials (same value set as before)
  if (t < 64) red[t] = partials[t];
  __syncthreads();
  if (t < 32) red[t] = fmaxf(red[t], red[t + 32]);
  __syncthreads();
  if (t < 16) red[t] = fmaxf(red[t], red[t + 16]);
  __syncthreads();
  if (t < 8)  red[t] = fmaxf(red[t], red[t + 8]);
  __syncthreads();
  if (t < 4)  red[t] = fmaxf(red[t], red[t + 4]);
  __syncthreads();
  if (t < 2)  red[t] = fmaxf(red[t], red[t + 2]);
  __syncthreads();
  if (t == 0) s_sf = fmaxf(red[0], red[1]) / 127.f;
  __syncthreads();
  float inv_sf = 1.f / s_sf;

  // quantize + stage into LDS
  #pragma unroll
  for (int r = 0; r < 4; r++) {
    int packed = 0;
    #pragma unroll
    for (int j = 0; j < 4; j++) {
      float rr = fminf(fmaxf(rintf(xv[r][j] * inv_sf), -128.f), 127.f);
      packed |= ((int)rr & 0xff) << (8 * j);
    }
    qxt[r][w + 1][g] = packed;
  }
  if (t < 64) {  // zero halo columns: 4 rows x 2 cols x 8 groups
    int r = t >> 4, col = ((t >> 3) & 1) * 33, g2 = t & 7;
    qxt[r][col][g2] = 0;
  }
  __syncthreads();

  // conv
  int wv = t >> 6, l = t & 63;
  int hs = l >> 5, ww = l & 31;
  int h = h0 + hs;

  int4 p[3][6];
  #pragma unroll
  for (int r = 0; r < 3; r++) {
    const int4* row = (const int4*)(&qxt[hs + r][ww][0]);  // 96 B: cols ww-1..ww+1
    #pragma unroll
    for (int k = 0; k < 6; k++) p[r][k] = row[k];
  }

  float scale = s_sf * sfsw[1];

  #pragma unroll
  for (int j = 0; j < 4; j++) {
    int o = __builtin_amdgcn_readfirstlane(ohalf * 16 + wv * 4 + j);  // wave-uniform
    const int* wr = (const int*)qw_r + o * 72;
    int acc = 0;
    #pragma unroll
    for (int ky = 0; ky < 3; ky++) {
      const int* wk = wr + ky * 24;
      #pragma unroll
      for (int k = 0; k < 6; k++) {
        int4 pp = p[ky][k];
        acc = dot4(pp.x, wk[k * 4 + 0], acc);
        acc = dot4(pp.y, wk[k * 4 + 1], acc);
        acc = dot4(pp.z, wk[k * 4 + 2], acc);
        acc = dot4(pp.w, wk[k * 4 + 3], acc);
      }
    }
    out[(n * 32 + o) * 1024 + h * 32 + ww] = scale * (float)acc + bias[o];
  }
}

extern "C" void kernel_launch(void* const* d_in, const int* in_sizes, int n_in,
                              void* d_out, int out_size, void* d_ws, size_t ws_size,
                              hipStream_t stream) {
  (void)in_sizes; (void)n_in; (void)out_size; (void)ws_size;
  const float* x    = (const float*)d_in[0];  // (8,32,32,32)
  const float* w    = (const float*)d_in[1];  // (32,32,3,3)
  const float* bias = (const float*)d_in[2];  // (32,)
  // d_in[3] (lut) unused: lut[i,j] = (i-128)*(j-128) analytically.
  float* out = (float*)d_out;

  char* ws = (char*)d_ws;
  float*       partials = (float*)(ws + 0);        // 64 floats
  float*       sfsw     = (float*)(ws + 512);      // [1] = sw
  signed char* qw_r     = (signed char*)(ws + 2048);   // 9216 B, [o][k9][c]

  k_absmax_wq<<<65, 256, 0, stream>>>((const float4*)x, w, partials, sfsw, qw_r);
  k_fused<<<256, 256, 0, stream>>>(x, partials, sfsw, qw_r, bias, out);
}